// Round 1
// baseline (1719.039 us; speedup 1.0000x reference)
//
#include <hip/hip_runtime.h>

#define N_NODES 50000
#define N_EDGES 800000

// ---------- order-preserving float<->uint for atomicMax on floats ----------
__device__ __forceinline__ unsigned ford(float f) {
  unsigned u = __float_as_uint(f);
  return (u & 0x80000000u) ? ~u : (u | 0x80000000u);
}
__device__ __forceinline__ float funord(unsigned u) {
  return (u & 0x80000000u) ? __uint_as_float(u & 0x7FFFFFFFu)
                           : __uint_as_float(~u);
}

// ---------- tiled fp32 GEMM: C[M,Nn] = A[M,K] @ B[K,Nn] ----------
template <int BM, int BN, int BK>
__global__ __launch_bounds__(256) void gemm_tile(
    const float* __restrict__ A, const float* __restrict__ B,
    float* __restrict__ C, int M, int Nn, int K) {
  __shared__ float As[BM][BK + 1];
  __shared__ float Bs[BK][BN];
  const int tid = threadIdx.x;
  const int tx = tid & 15;   // 16 cols of threads
  const int ty = tid >> 4;   // 16 rows of threads
  const int rowBase = blockIdx.x * BM;
  const int colBase = blockIdx.y * BN;
  float acc[4][4] = {};
  for (int k0 = 0; k0 < K; k0 += BK) {
#pragma unroll
    for (int i = tid; i < BM * BK / 4; i += 256) {
      int r = i / (BK / 4);
      int c = (i % (BK / 4)) * 4;
      int row = rowBase + r;
      if (row > M - 1) row = M - 1;  // clamp (stores are guarded)
      float4 v = *(const float4*)&A[(size_t)row * K + k0 + c];
      As[r][c] = v.x; As[r][c + 1] = v.y; As[r][c + 2] = v.z; As[r][c + 3] = v.w;
    }
#pragma unroll
    for (int i = tid; i < BK * BN / 4; i += 256) {
      int r = i / (BN / 4);
      int c = (i % (BN / 4)) * 4;
      *(float4*)&Bs[r][c] = *(const float4*)&B[(size_t)(k0 + r) * Nn + colBase + c];
    }
    __syncthreads();
#pragma unroll
    for (int k = 0; k < BK; ++k) {
      float a0 = As[ty * 4 + 0][k], a1 = As[ty * 4 + 1][k];
      float a2 = As[ty * 4 + 2][k], a3 = As[ty * 4 + 3][k];
      float4 b = *(const float4*)&Bs[k][tx * 4];
      acc[0][0] += a0 * b.x; acc[0][1] += a0 * b.y; acc[0][2] += a0 * b.z; acc[0][3] += a0 * b.w;
      acc[1][0] += a1 * b.x; acc[1][1] += a1 * b.y; acc[1][2] += a1 * b.z; acc[1][3] += a1 * b.w;
      acc[2][0] += a2 * b.x; acc[2][1] += a2 * b.y; acc[2][2] += a2 * b.z; acc[2][3] += a2 * b.w;
      acc[3][0] += a3 * b.x; acc[3][1] += a3 * b.y; acc[3][2] += a3 * b.z; acc[3][3] += a3 * b.w;
    }
    __syncthreads();
  }
#pragma unroll
  for (int i = 0; i < 4; ++i) {
    int row = rowBase + ty * 4 + i;
    if (row < M) {
      float4 v = make_float4(acc[i][0], acc[i][1], acc[i][2], acc[i][3]);
      *(float4*)&C[(size_t)row * Nn + colBase + tx * 4] = v;
    }
  }
}

// ---------- attention dot products, layer 1 (H=4, C=64): one wave per node ----------
__global__ __launch_bounds__(256) void attdot4(
    const float* __restrict__ h1, const float* __restrict__ att_src,
    const float* __restrict__ att_dst, float* __restrict__ a_src,
    float* __restrict__ a_dst, int n) {
  int node = blockIdx.x * 4 + (threadIdx.x >> 6);
  int lane = threadIdx.x & 63;
  if (node >= n) return;
  const float* hrow = h1 + (size_t)node * 256;
#pragma unroll
  for (int h = 0; h < 4; ++h) {
    float v = hrow[h * 64 + lane];
    float s = v * att_src[h * 64 + lane];
    float d = v * att_dst[h * 64 + lane];
#pragma unroll
    for (int off = 32; off > 0; off >>= 1) {
      s += __shfl_xor(s, off);
      d += __shfl_xor(d, off);
    }
    if (lane == 0) {
      a_src[node * 4 + h] = s;
      a_dst[node * 4 + h] = d;
    }
  }
}

// ---------- attention dot products, layer 2 (H=1, C=64) ----------
__global__ __launch_bounds__(256) void attdot1h(
    const float* __restrict__ h2, const float* __restrict__ att_src,
    const float* __restrict__ att_dst, float* __restrict__ a_src,
    float* __restrict__ a_dst, int n) {
  int node = blockIdx.x * 4 + (threadIdx.x >> 6);
  int lane = threadIdx.x & 63;
  if (node >= n) return;
  float v = h2[(size_t)node * 64 + lane];
  float s = v * att_src[lane];
  float d = v * att_dst[lane];
#pragma unroll
  for (int off = 32; off > 0; off >>= 1) {
    s += __shfl_xor(s, off);
    d += __shfl_xor(d, off);
  }
  if (lane == 0) {
    a_src[node] = s;
    a_dst[node] = d;
  }
}

// ---------- edge score + segment max (H=4) ----------
__global__ __launch_bounds__(256) void edge_score4(
    const int* __restrict__ ei, const float* __restrict__ a_src,
    const float* __restrict__ a_dst, float* __restrict__ e_out,
    unsigned* __restrict__ m, int E) {
  int e = blockIdx.x * blockDim.x + threadIdx.x;
  if (e >= E) return;
  int s = ei[e], d = ei[E + e];
  float4 as = *(const float4*)&a_src[s * 4];
  float4 ad = *(const float4*)&a_dst[d * 4];
  float4 ev;
  ev.x = as.x + ad.x; ev.x = ev.x > 0.f ? ev.x : 0.2f * ev.x;
  ev.y = as.y + ad.y; ev.y = ev.y > 0.f ? ev.y : 0.2f * ev.y;
  ev.z = as.z + ad.z; ev.z = ev.z > 0.f ? ev.z : 0.2f * ev.z;
  ev.w = as.w + ad.w; ev.w = ev.w > 0.f ? ev.w : 0.2f * ev.w;
  *(float4*)&e_out[(size_t)e * 4] = ev;
  atomicMax(&m[d * 4 + 0], ford(ev.x));
  atomicMax(&m[d * 4 + 1], ford(ev.y));
  atomicMax(&m[d * 4 + 2], ford(ev.z));
  atomicMax(&m[d * 4 + 3], ford(ev.w));
}

// ---------- edge exp + segment sum (H=4); e_out overwritten with exp ----------
__global__ __launch_bounds__(256) void edge_exp4(
    const int* __restrict__ ei, float* __restrict__ e_out,
    const unsigned* __restrict__ m, float* __restrict__ denom, int E) {
  int e = blockIdx.x * blockDim.x + threadIdx.x;
  if (e >= E) return;
  int d = ei[E + e];
  float4 ev = *(const float4*)&e_out[(size_t)e * 4];
  uint4 mu = *(const uint4*)&m[d * 4];
  float4 ex;
  ex.x = expf(ev.x - funord(mu.x));
  ex.y = expf(ev.y - funord(mu.y));
  ex.z = expf(ev.z - funord(mu.z));
  ex.w = expf(ev.w - funord(mu.w));
  *(float4*)&e_out[(size_t)e * 4] = ex;
  atomicAdd(&denom[d * 4 + 0], ex.x);
  atomicAdd(&denom[d * 4 + 1], ex.y);
  atomicAdd(&denom[d * 4 + 2], ex.z);
  atomicAdd(&denom[d * 4 + 3], ex.w);
}

// ---------- edge score/exp for H=1 ----------
__global__ __launch_bounds__(256) void edge_score1h(
    const int* __restrict__ ei, const float* __restrict__ a_src,
    const float* __restrict__ a_dst, float* __restrict__ e_out,
    unsigned* __restrict__ m, int E) {
  int e = blockIdx.x * blockDim.x + threadIdx.x;
  if (e >= E) return;
  int s = ei[e], d = ei[E + e];
  float v = a_src[s] + a_dst[d];
  v = v > 0.f ? v : 0.2f * v;
  e_out[e] = v;
  atomicMax(&m[d], ford(v));
}

__global__ __launch_bounds__(256) void edge_exp1h(
    const int* __restrict__ ei, float* __restrict__ e_out,
    const unsigned* __restrict__ m, float* __restrict__ denom, int E) {
  int e = blockIdx.x * blockDim.x + threadIdx.x;
  if (e >= E) return;
  int d = ei[E + e];
  float ex = expf(e_out[e] - funord(m[d]));
  e_out[e] = ex;
  atomicAdd(&denom[d], ex);
}

// ---------- aggregation L1: one block (256 thr) per edge, 256 feats ----------
__global__ __launch_bounds__(256) void aggregate4(
    const int* __restrict__ ei, const float* __restrict__ h1,
    const float* __restrict__ ex, const float* __restrict__ denom,
    float* __restrict__ out, int E) {
  int e = blockIdx.x;
  int t = threadIdx.x;
  int s = ei[e], d = ei[E + e];
  int h = t >> 6;
  float alpha = ex[(size_t)e * 4 + h] / (denom[d * 4 + h] + 1e-16f);
  atomicAdd(&out[(size_t)d * 256 + t], h1[(size_t)s * 256 + t] * alpha);
}

// ---------- aggregation L2: 4 edges per block (wave each), 64 feats ----------
__global__ __launch_bounds__(256) void aggregate1h(
    const int* __restrict__ ei, const float* __restrict__ h2,
    const float* __restrict__ ex, const float* __restrict__ denom,
    float* __restrict__ out, int E) {
  int e = blockIdx.x * 4 + (threadIdx.x >> 6);
  int c = threadIdx.x & 63;
  if (e >= E) return;
  int s = ei[e], d = ei[E + e];
  float alpha = ex[e] / (denom[d] + 1e-16f);
  atomicAdd(&out[(size_t)d * 64 + c], h2[(size_t)s * 64 + c] * alpha);
}

// ---------- bias + ELU ----------
__global__ __launch_bounds__(256) void elu_bias(
    const float* __restrict__ in, const float* __restrict__ b,
    float* __restrict__ outp, int total) {
  int i = blockIdx.x * blockDim.x + threadIdx.x;
  if (i >= total) return;
  float v = in[i] + b[i & 255];
  outp[i] = v > 0.f ? v : expm1f(v);
}

// ---------- final MLP head: thread per node ----------
__global__ __launch_bounds__(256) void mlp_head(
    const float* __restrict__ emb_in, const float* __restrict__ b2,
    const float* __restrict__ mw1, const float* __restrict__ mb1,
    const float* __restrict__ mw2, const float* __restrict__ mb2,
    float* __restrict__ outp, int n) {
  __shared__ float w1s[64 * 64];
  __shared__ float w2s[64 * 40];
  __shared__ float b1s[64];
  __shared__ float b2s[40];
  int t = threadIdx.x;
  for (int i = t; i < 64 * 64; i += 256) w1s[i] = mw1[i];
  for (int i = t; i < 64 * 40; i += 256) w2s[i] = mw2[i];
  if (t < 64) b1s[t] = mb1[t];
  if (t < 40) b2s[t] = mb2[t];
  __syncthreads();
  int node = blockIdx.x * 256 + t;
  if (node >= n) return;
  float emb[64];
#pragma unroll
  for (int i = 0; i < 64; ++i) emb[i] = emb_in[(size_t)node * 64 + i] + b2[i];
  float hid[64];
#pragma unroll
  for (int j = 0; j < 64; ++j) {
    float s = b1s[j];
#pragma unroll
    for (int i = 0; i < 64; ++i) s += emb[i] * w1s[i * 64 + j];
    hid[j] = s > 0.f ? s : 0.f;
  }
#pragma unroll
  for (int k = 0; k < 40; ++k) {
    float s = b2s[k];
#pragma unroll
    for (int j = 0; j < 64; ++j) s += hid[j] * w2s[j * 40 + k];
    outp[(size_t)node * 40 + k] = s;
  }
}

extern "C" void kernel_launch(void* const* d_in, const int* in_sizes, int n_in,
                              void* d_out, int out_size, void* d_ws, size_t ws_size,
                              hipStream_t stream) {
  const float* x        = (const float*)d_in[0];
  const int*   ei       = (const int*)d_in[1];
  const float* W1       = (const float*)d_in[2];
  const float* att_src1 = (const float*)d_in[3];
  const float* att_dst1 = (const float*)d_in[4];
  const float* b1       = (const float*)d_in[5];
  const float* W2       = (const float*)d_in[6];
  const float* att_src2 = (const float*)d_in[7];
  const float* att_dst2 = (const float*)d_in[8];
  const float* b2       = (const float*)d_in[9];
  const float* mw1      = (const float*)d_in[10];
  const float* mb1      = (const float*)d_in[11];
  const float* mw2      = (const float*)d_in[12];
  const float* mb2      = (const float*)d_in[13];
  float* out = (float*)d_out;

  const int N = N_NODES, E = N_EDGES;
  float* base = (float*)d_ws;
  size_t o = 0;
  // ---- zero-initialized span (single memset) ----
  float*    out1   = base + o; o += (size_t)N * 256;
  unsigned* m1     = (unsigned*)(base + o); o += (size_t)N * 4;
  float*    denom1 = base + o; o += (size_t)N * 4;
  float*    out2   = base + o; o += (size_t)N * 64;
  unsigned* m2     = (unsigned*)(base + o); o += N;
  float*    denom2 = base + o; o += N;
  size_t zero_floats = o;
  // ---- uninitialized scratch ----
  float* h1    = base + o; o += (size_t)N * 256;
  float* e1    = base + o; o += (size_t)E * 4;   // scores, then exp
  float* asrc1 = base + o; o += (size_t)N * 4;
  float* adst1 = base + o; o += (size_t)N * 4;
  float* h2    = base + o; o += (size_t)N * 64;
  float* e2    = base + o; o += E;
  float* asrc2 = base + o; o += N;
  float* adst2 = base + o; o += N;

  hipMemsetAsync(d_ws, 0, zero_floats * sizeof(float), stream);

  // ---- layer 1 ----
  dim3 g1((N + 63) / 64, 4);
  gemm_tile<64, 64, 32><<<g1, 256, 0, stream>>>(x, W1, h1, N, 256, 512);
  attdot4<<<(N + 3) / 4, 256, 0, stream>>>(h1, att_src1, att_dst1, asrc1, adst1, N);
  edge_score4<<<(E + 255) / 256, 256, 0, stream>>>(ei, asrc1, adst1, e1, m1, E);
  edge_exp4<<<(E + 255) / 256, 256, 0, stream>>>(ei, e1, m1, denom1, E);
  aggregate4<<<E, 256, 0, stream>>>(ei, h1, e1, denom1, out1, E);
  elu_bias<<<(N * 256 + 255) / 256, 256, 0, stream>>>(out1, b1, h1, N * 256);

  // ---- layer 2 ----
  dim3 g2((N + 63) / 64, 1);
  gemm_tile<64, 64, 32><<<g2, 256, 0, stream>>>(h1, W2, h2, N, 64, 256);
  attdot1h<<<(N + 3) / 4, 256, 0, stream>>>(h2, att_src2, att_dst2, asrc2, adst2, N);
  edge_score1h<<<(E + 255) / 256, 256, 0, stream>>>(ei, asrc2, adst2, e2, m2, E);
  edge_exp1h<<<(E + 255) / 256, 256, 0, stream>>>(ei, e2, m2, denom2, E);
  aggregate1h<<<(E + 3) / 4, 256, 0, stream>>>(ei, h2, e2, denom2, out2, E);

  // ---- MLP head ----
  mlp_head<<<(N + 255) / 256, 256, 0, stream>>>(out2, b2, mw1, mb1, mw2, mb2, out, N);
}

// Round 2
// 771.842 us; speedup vs baseline: 2.2272x; 2.2272x over previous
//
#include <hip/hip_runtime.h>

#define N_NODES 50000
#define N_EDGES 800000
#define SCAN_B 196   // ceil(50000/256)

// ============================================================
// Counting sort by dst: hist -> 2-level exclusive scan -> scatter
// ============================================================
__global__ __launch_bounds__(256) void hist_k(const int* __restrict__ ei,
                                              int* __restrict__ cnt) {
  int e = blockIdx.x * 256 + threadIdx.x;
  if (e >= N_EDGES) return;
  atomicAdd(&cnt[ei[N_EDGES + e]], 1);
}

__global__ __launch_bounds__(256) void scan1(const int* __restrict__ cnt,
                                             int* __restrict__ offs,
                                             int* __restrict__ bsum) {
  __shared__ int sh[256];
  int t = threadIdx.x;
  int i = blockIdx.x * 256 + t;
  int v = (i < N_NODES) ? cnt[i] : 0;
  sh[t] = v;
  __syncthreads();
  for (int off = 1; off < 256; off <<= 1) {
    int add = (t >= off) ? sh[t - off] : 0;
    __syncthreads();
    sh[t] += add;
    __syncthreads();
  }
  if (i < N_NODES) offs[i] = sh[t] - v;  // exclusive
  if (t == 255) bsum[blockIdx.x] = sh[255];
}

__global__ __launch_bounds__(256) void scan2(const int* __restrict__ bsum,
                                             int* __restrict__ bofs) {
  __shared__ int sh[256];
  int t = threadIdx.x;
  int v = (t < SCAN_B) ? bsum[t] : 0;
  sh[t] = v;
  __syncthreads();
  for (int off = 1; off < 256; off <<= 1) {
    int add = (t >= off) ? sh[t - off] : 0;
    __syncthreads();
    sh[t] += add;
    __syncthreads();
  }
  if (t < SCAN_B) bofs[t] = sh[t] - v;
}

__global__ __launch_bounds__(256) void scan3(int* __restrict__ offs,
                                             const int* __restrict__ bofs) {
  int i = blockIdx.x * 256 + threadIdx.x;
  if (i < N_NODES) offs[i] += bofs[blockIdx.x];
  if (i == 0) offs[N_NODES] = N_EDGES;
}

__global__ __launch_bounds__(256) void scatter_k(const int* __restrict__ ei,
                                                 const int* __restrict__ offs,
                                                 int* __restrict__ cur,
                                                 int* __restrict__ ssort) {
  int e = blockIdx.x * 256 + threadIdx.x;
  if (e >= N_EDGES) return;
  int d = ei[N_EDGES + e];
  int p = offs[d] + atomicAdd(&cur[d], 1);
  ssort[p] = ei[e];  // src id in dst-sorted order
}

// ============================================================
// tiled fp32 GEMM: C[M,Nn] = A[M,K] @ B[K,Nn]
// ============================================================
template <int BM, int BN, int BK>
__global__ __launch_bounds__(256) void gemm_tile(
    const float* __restrict__ A, const float* __restrict__ B,
    float* __restrict__ C, int M, int Nn, int K) {
  __shared__ float As[BM][BK + 1];
  __shared__ float Bs[BK][BN];
  const int tid = threadIdx.x;
  const int tx = tid & 15;
  const int ty = tid >> 4;
  const int rowBase = blockIdx.x * BM;
  const int colBase = blockIdx.y * BN;
  float acc[4][4] = {};
  for (int k0 = 0; k0 < K; k0 += BK) {
#pragma unroll
    for (int i = tid; i < BM * BK / 4; i += 256) {
      int r = i / (BK / 4);
      int c = (i % (BK / 4)) * 4;
      int row = rowBase + r;
      if (row > M - 1) row = M - 1;
      float4 v = *(const float4*)&A[(size_t)row * K + k0 + c];
      As[r][c] = v.x; As[r][c + 1] = v.y; As[r][c + 2] = v.z; As[r][c + 3] = v.w;
    }
#pragma unroll
    for (int i = tid; i < BK * BN / 4; i += 256) {
      int r = i / (BN / 4);
      int c = (i % (BN / 4)) * 4;
      *(float4*)&Bs[r][c] = *(const float4*)&B[(size_t)(k0 + r) * Nn + colBase + c];
    }
    __syncthreads();
#pragma unroll
    for (int k = 0; k < BK; ++k) {
      float a0 = As[ty * 4 + 0][k], a1 = As[ty * 4 + 1][k];
      float a2 = As[ty * 4 + 2][k], a3 = As[ty * 4 + 3][k];
      float4 b = *(const float4*)&Bs[k][tx * 4];
      acc[0][0] += a0 * b.x; acc[0][1] += a0 * b.y; acc[0][2] += a0 * b.z; acc[0][3] += a0 * b.w;
      acc[1][0] += a1 * b.x; acc[1][1] += a1 * b.y; acc[1][2] += a1 * b.z; acc[1][3] += a1 * b.w;
      acc[2][0] += a2 * b.x; acc[2][1] += a2 * b.y; acc[2][2] += a2 * b.z; acc[2][3] += a2 * b.w;
      acc[3][0] += a3 * b.x; acc[3][1] += a3 * b.y; acc[3][2] += a3 * b.z; acc[3][3] += a3 * b.w;
    }
    __syncthreads();
  }
#pragma unroll
  for (int i = 0; i < 4; ++i) {
    int row = rowBase + ty * 4 + i;
    if (row < M) {
      float4 v = make_float4(acc[i][0], acc[i][1], acc[i][2], acc[i][3]);
      *(float4*)&C[(size_t)row * Nn + colBase + tx * 4] = v;
    }
  }
}

// ============================================================
// attention dot products
// ============================================================
__global__ __launch_bounds__(256) void attdot4(
    const float* __restrict__ h1, const float* __restrict__ att_src,
    const float* __restrict__ att_dst, float* __restrict__ a_src,
    float* __restrict__ a_dst, int n) {
  int node = blockIdx.x * 4 + (threadIdx.x >> 6);
  int lane = threadIdx.x & 63;
  if (node >= n) return;
  const float* hrow = h1 + (size_t)node * 256;
#pragma unroll
  for (int h = 0; h < 4; ++h) {
    float v = hrow[h * 64 + lane];
    float s = v * att_src[h * 64 + lane];
    float d = v * att_dst[h * 64 + lane];
#pragma unroll
    for (int off = 32; off > 0; off >>= 1) {
      s += __shfl_xor(s, off);
      d += __shfl_xor(d, off);
    }
    if (lane == 0) {
      a_src[node * 4 + h] = s;
      a_dst[node * 4 + h] = d;
    }
  }
}

__global__ __launch_bounds__(256) void attdot1h(
    const float* __restrict__ h2, const float* __restrict__ att_src,
    const float* __restrict__ att_dst, float* __restrict__ a_src,
    float* __restrict__ a_dst, int n) {
  int node = blockIdx.x * 4 + (threadIdx.x >> 6);
  int lane = threadIdx.x & 63;
  if (node >= n) return;
  float v = h2[(size_t)node * 64 + lane];
  float s = v * att_src[lane];
  float d = v * att_dst[lane];
#pragma unroll
  for (int off = 32; off > 0; off >>= 1) {
    s += __shfl_xor(s, off);
    d += __shfl_xor(d, off);
  }
  if (lane == 0) {
    a_src[node] = s;
    a_dst[node] = d;
  }
}

// ============================================================
// Fused softmax + aggregation, layer 1 (H=4, C=64).
// One block (256 thr) per dst node; online softmax over CSR edge list;
// output row written once; bias+ELU fused.
// ============================================================
__global__ __launch_bounds__(256) void agg_l1(
    const int* __restrict__ offs, const int* __restrict__ ssort,
    const float* __restrict__ asrc, const float* __restrict__ adst,
    const float* __restrict__ h1, const float* __restrict__ b1,
    float* __restrict__ outp) {
  const int d = blockIdx.x;
  const int t = threadIdx.x;
  const int h = t >> 6;
  __shared__ int s_src[256];
  __shared__ float s_sc[256 * 4];  // [edge][head]
  __shared__ float s_m[4];
  const int row0 = offs[d], row1 = offs[d + 1];
  const float4 ad4 = *(const float4*)&adst[d * 4];
  float m = -INFINITY, acc = 0.f, denom = 0.f;

  for (int j0 = row0; j0 < row1; j0 += 256) {
    const int n = min(256, row1 - j0);
    if (t < n) {
      int s = ssort[j0 + t];
      s_src[t] = s;
      float4 as = *(const float4*)&asrc[s * 4];
      float4 sc;
      sc.x = as.x + ad4.x; sc.x = sc.x > 0.f ? sc.x : 0.2f * sc.x;
      sc.y = as.y + ad4.y; sc.y = sc.y > 0.f ? sc.y : 0.2f * sc.y;
      sc.z = as.z + ad4.z; sc.z = sc.z > 0.f ? sc.z : 0.2f * sc.z;
      sc.w = as.w + ad4.w; sc.w = sc.w > 0.f ? sc.w : 0.2f * sc.w;
      *(float4*)&s_sc[t * 4] = sc;
    }
    __syncthreads();
    // chunk max for own head (deg is small; serial loop is fine)
    float mc = -INFINITY;
    for (int j = 0; j < n; ++j) mc = fmaxf(mc, s_sc[j * 4 + h]);
    float mn = fmaxf(m, mc);
    float scale = expf(m - mn);  // m=-inf on first chunk -> 0 (acc,denom are 0)
    acc *= scale;
    denom *= scale;
    m = mn;
    if ((t & 63) == 0) s_m[h] = mn;
    __syncthreads();
    // j-parallel exp over all heads
    for (int j = t; j < n * 4; j += 256)
      s_sc[j] = expf(s_sc[j] - s_m[j & 3]);
    __syncthreads();
    // denominator (redundant across the 64 threads of a head) + features
    for (int j = 0; j < n; ++j) {
      float exv = s_sc[j * 4 + h];
      denom += exv;
      acc += h1[(size_t)s_src[j] * 256 + t] * exv;
    }
    __syncthreads();  // protect LDS before next chunk
  }
  float val = (denom > 0.f ? acc / denom : 0.f) + b1[t];
  outp[(size_t)d * 256 + t] = val > 0.f ? val : expm1f(val);
}

// ============================================================
// Fused softmax + aggregation, layer 2 (H=1, C=64).
// One wave per dst node (4 per block); shuffle-based, no LDS; bias fused.
// ============================================================
__global__ __launch_bounds__(256) void agg_l2(
    const int* __restrict__ offs, const int* __restrict__ ssort,
    const float* __restrict__ asrc, const float* __restrict__ adst,
    const float* __restrict__ h2, const float* __restrict__ b2,
    float* __restrict__ outp, int n_nodes) {
  int d = blockIdx.x * 4 + (threadIdx.x >> 6);
  int lane = threadIdx.x & 63;
  if (d >= n_nodes) return;
  const int row0 = offs[d], row1 = offs[d + 1];
  const float ad = adst[d];
  float m = -INFINITY, acc = 0.f, denom = 0.f;

  for (int j0 = row0; j0 < row1; j0 += 64) {
    const int n = min(64, row1 - j0);
    int s = 0;
    float sc = -INFINITY;
    if (lane < n) {
      s = ssort[j0 + lane];
      sc = asrc[s] + ad;
      sc = sc > 0.f ? sc : 0.2f * sc;
    }
    float mc = sc;
#pragma unroll
    for (int off = 32; off > 0; off >>= 1) mc = fmaxf(mc, __shfl_xor(mc, off));
    float mn = fmaxf(m, mc);
    float scale = expf(m - mn);
    acc *= scale;
    denom *= scale;
    m = mn;
    float ex = (lane < n) ? expf(sc - mn) : 0.f;
    float ds = ex;
#pragma unroll
    for (int off = 32; off > 0; off >>= 1) ds += __shfl_xor(ds, off);
    denom += ds;
    for (int j = 0; j < n; ++j) {
      int sj = __shfl(s, j);
      float exj = __shfl(ex, j);
      acc += h2[(size_t)sj * 64 + lane] * exj;
    }
  }
  float val = (denom > 0.f ? acc / denom : 0.f) + b2[lane];
  outp[(size_t)d * 64 + lane] = val;
}

// ============================================================
// final MLP head (emb already has b2 added)
// ============================================================
__global__ __launch_bounds__(256) void mlp_head(
    const float* __restrict__ emb_in,
    const float* __restrict__ mw1, const float* __restrict__ mb1,
    const float* __restrict__ mw2, const float* __restrict__ mb2,
    float* __restrict__ outp, int n) {
  __shared__ float w1s[64 * 64];
  __shared__ float w2s[64 * 40];
  __shared__ float b1s[64];
  __shared__ float b2s[40];
  int t = threadIdx.x;
  for (int i = t; i < 64 * 64; i += 256) w1s[i] = mw1[i];
  for (int i = t; i < 64 * 40; i += 256) w2s[i] = mw2[i];
  if (t < 64) b1s[t] = mb1[t];
  if (t < 40) b2s[t] = mb2[t];
  __syncthreads();
  int node = blockIdx.x * 256 + t;
  if (node >= n) return;
  float emb[64];
#pragma unroll
  for (int i = 0; i < 64; ++i) emb[i] = emb_in[(size_t)node * 64 + i];
  float hid[64];
#pragma unroll
  for (int j = 0; j < 64; ++j) {
    float s = b1s[j];
#pragma unroll
    for (int i = 0; i < 64; ++i) s += emb[i] * w1s[i * 64 + j];
    hid[j] = s > 0.f ? s : 0.f;
  }
#pragma unroll
  for (int k = 0; k < 40; ++k) {
    float s = b2s[k];
#pragma unroll
    for (int j = 0; j < 64; ++j) s += hid[j] * w2s[j * 40 + k];
    outp[(size_t)node * 40 + k] = s;
  }
}

extern "C" void kernel_launch(void* const* d_in, const int* in_sizes, int n_in,
                              void* d_out, int out_size, void* d_ws, size_t ws_size,
                              hipStream_t stream) {
  const float* x        = (const float*)d_in[0];
  const int*   ei       = (const int*)d_in[1];
  const float* W1       = (const float*)d_in[2];
  const float* att_src1 = (const float*)d_in[3];
  const float* att_dst1 = (const float*)d_in[4];
  const float* b1       = (const float*)d_in[5];
  const float* W2       = (const float*)d_in[6];
  const float* att_src2 = (const float*)d_in[7];
  const float* att_dst2 = (const float*)d_in[8];
  const float* b2       = (const float*)d_in[9];
  const float* mw1      = (const float*)d_in[10];
  const float* mb1      = (const float*)d_in[11];
  const float* mw2      = (const float*)d_in[12];
  const float* mb2      = (const float*)d_in[13];
  float* out = (float*)d_out;

  const int N = N_NODES, E = N_EDGES;
  char* base = (char*)d_ws;
  size_t o = 0;
  auto alloc = [&](size_t n_elems) {
    void* p = base + o;
    o += n_elems * 4;
    return p;
  };
  // ---- zero-initialized span (single small memset) ----
  int* cnt = (int*)alloc(N);
  int* cur = (int*)alloc(N);
  size_t zero_bytes = o;
  // ---- uninitialized scratch ----
  int*   offs  = (int*)alloc(N + 2);
  int*   bsum  = (int*)alloc(256);
  int*   bofs  = (int*)alloc(256);
  int*   ssort = (int*)alloc(E);
  float* h1    = (float*)alloc((size_t)N * 256);
  float* h1e   = (float*)alloc((size_t)N * 256);
  float* asrc1 = (float*)alloc((size_t)N * 4);
  float* adst1 = (float*)alloc((size_t)N * 4);
  float* h2    = (float*)alloc((size_t)N * 64);
  float* emb   = (float*)alloc((size_t)N * 64);
  float* asrc2 = (float*)alloc(N);
  float* adst2 = (float*)alloc(N);

  hipMemsetAsync(d_ws, 0, zero_bytes, stream);

  const int EB = (E + 255) / 256;

  // ---- build dst-sorted CSR (shared by both layers) ----
  hist_k<<<EB, 256, 0, stream>>>(ei, cnt);
  scan1<<<SCAN_B, 256, 0, stream>>>(cnt, offs, bsum);
  scan2<<<1, 256, 0, stream>>>(bsum, bofs);
  scan3<<<SCAN_B, 256, 0, stream>>>(offs, bofs);
  scatter_k<<<EB, 256, 0, stream>>>(ei, offs, cur, ssort);

  // ---- layer 1 ----
  dim3 g1((N + 63) / 64, 4);
  gemm_tile<64, 64, 32><<<g1, 256, 0, stream>>>(x, W1, h1, N, 256, 512);
  attdot4<<<(N + 3) / 4, 256, 0, stream>>>(h1, att_src1, att_dst1, asrc1, adst1, N);
  agg_l1<<<N, 256, 0, stream>>>(offs, ssort, asrc1, adst1, h1, b1, h1e);

  // ---- layer 2 ----
  dim3 g2((N + 63) / 64, 1);
  gemm_tile<64, 64, 32><<<g2, 256, 0, stream>>>(h1e, W2, h2, N, 64, 256);
  attdot1h<<<(N + 3) / 4, 256, 0, stream>>>(h2, att_src2, att_dst2, asrc2, adst2, N);
  agg_l2<<<(N + 3) / 4, 256, 0, stream>>>(offs, ssort, asrc2, adst2, h2, b2, emb, N);

  // ---- MLP head ----
  mlp_head<<<(N + 255) / 256, 256, 0, stream>>>(emb, mw1, mb1, mw2, mb2, out, N);
}

// Round 3
// 623.625 us; speedup vs baseline: 2.7565x; 1.2377x over previous
//
#include <hip/hip_runtime.h>

#define N_NODES 50000
#define N_EDGES 800000
#define SCAN_B 196   // ceil(50000/256)

typedef short bf16x8 __attribute__((ext_vector_type(8)));
typedef float f32x4 __attribute__((ext_vector_type(4)));

// ============================================================
// Counting sort by dst: hist -> 2-level exclusive scan -> scatter
// ============================================================
__global__ __launch_bounds__(256) void hist_k(const int* __restrict__ ei,
                                              int* __restrict__ cnt) {
  int e = blockIdx.x * 256 + threadIdx.x;
  if (e >= N_EDGES) return;
  atomicAdd(&cnt[ei[N_EDGES + e]], 1);
}

__global__ __launch_bounds__(256) void scan1(const int* __restrict__ cnt,
                                             int* __restrict__ offs,
                                             int* __restrict__ bsum) {
  __shared__ int sh[256];
  int t = threadIdx.x;
  int i = blockIdx.x * 256 + t;
  int v = (i < N_NODES) ? cnt[i] : 0;
  sh[t] = v;
  __syncthreads();
  for (int off = 1; off < 256; off <<= 1) {
    int add = (t >= off) ? sh[t - off] : 0;
    __syncthreads();
    sh[t] += add;
    __syncthreads();
  }
  if (i < N_NODES) offs[i] = sh[t] - v;  // exclusive
  if (t == 255) bsum[blockIdx.x] = sh[255];
}

__global__ __launch_bounds__(256) void scan2(const int* __restrict__ bsum,
                                             int* __restrict__ bofs) {
  __shared__ int sh[256];
  int t = threadIdx.x;
  int v = (t < SCAN_B) ? bsum[t] : 0;
  sh[t] = v;
  __syncthreads();
  for (int off = 1; off < 256; off <<= 1) {
    int add = (t >= off) ? sh[t - off] : 0;
    __syncthreads();
    sh[t] += add;
    __syncthreads();
  }
  if (t < SCAN_B) bofs[t] = sh[t] - v;
}

__global__ __launch_bounds__(256) void scan3(int* __restrict__ offs,
                                             const int* __restrict__ bofs) {
  int i = blockIdx.x * 256 + threadIdx.x;
  if (i < N_NODES) offs[i] += bofs[blockIdx.x];
  if (i == 0) offs[N_NODES] = N_EDGES;
}

__global__ __launch_bounds__(256) void scatter_k(const int* __restrict__ ei,
                                                 const int* __restrict__ offs,
                                                 int* __restrict__ cur,
                                                 int* __restrict__ ssort) {
  int e = blockIdx.x * 256 + threadIdx.x;
  if (e >= N_EDGES) return;
  int d = ei[N_EDGES + e];
  int p = offs[d] + atomicAdd(&cur[d], 1);
  ssort[p] = ei[e];
}

// ============================================================
// fp32 GEMM via split-bf16 MFMA (3-pass hi/lo emulation).
// C[M,Nn] = A[M,K] @ B[K,Nn], K % 32 == 0.
// BM=128, 256 threads (4 waves in WGM x WGN grid).
// ============================================================
__device__ __forceinline__ void split2(float x, short& hi, short& lo) {
  unsigned u = __float_as_uint(x);
  unsigned short h = (unsigned short)(u >> 16);          // truncate to bf16
  float hf = __uint_as_float((unsigned)h << 16);
  float r = x - hf;
  unsigned short l = (unsigned short)(__float_as_uint(r) >> 16);
  hi = (short)h;
  lo = (short)l;
}

template <int BN, int WGM, int WGN>
__global__ __launch_bounds__(256) void gemm_mfma(
    const float* __restrict__ A, const float* __restrict__ B,
    float* __restrict__ C, int M, int Nn, int K) {
  constexpr int BM = 128;
  constexpr int WM = BM / WGM;
  constexpr int WN = BN / WGN;
  constexpr int MT = WM / 16;
  constexpr int NT = WN / 16;
  constexpr int LDA = 40;           // 32 + 8 pad (16B-aligned rows, 2-way banks)
  constexpr int KPER = BN / 8;      // B k-rows per staging thread

  __shared__ short Ah[BM][LDA], Al[BM][LDA];
  __shared__ short Bh[BN][LDA], Bl[BN][LDA];

  const int tid = threadIdx.x;
  const int wave = tid >> 6;
  const int lane = tid & 63;
  const int quad = lane >> 4;
  const int l16 = lane & 15;
  const int wm = (wave / WGN) * WM;
  const int wn = (wave % WGN) * WN;
  const int rowBase = blockIdx.x * BM;
  const int colBase = blockIdx.y * BN;

  // staging assignments
  const int ra = tid >> 1;                 // A row in tile
  const int apart = (tid & 1) * 16;        // A float offset within BK
  const int nb = tid & (BN - 1);           // B col in tile
  const int kb = (tid / BN) * KPER;        // B k-row start

  const int arow = min(rowBase + ra, M - 1);
  const float* aptr = A + (size_t)arow * K + apart;

  f32x4 acc[MT][NT] = {};

  for (int k0 = 0; k0 < K; k0 += 32) {
    // ---- stage A (128 x 32 fp32 -> split bf16) ----
    {
      alignas(16) short h[16], l[16];
      const float4* a4 = (const float4*)(aptr + k0);
#pragma unroll
      for (int i = 0; i < 4; ++i) {
        float4 v = a4[i];
        split2(v.x, h[i * 4 + 0], l[i * 4 + 0]);
        split2(v.y, h[i * 4 + 1], l[i * 4 + 1]);
        split2(v.z, h[i * 4 + 2], l[i * 4 + 2]);
        split2(v.w, h[i * 4 + 3], l[i * 4 + 3]);
      }
      *(bf16x8*)&Ah[ra][apart]     = ((bf16x8*)h)[0];
      *(bf16x8*)&Ah[ra][apart + 8] = ((bf16x8*)h)[1];
      *(bf16x8*)&Al[ra][apart]     = ((bf16x8*)l)[0];
      *(bf16x8*)&Al[ra][apart + 8] = ((bf16x8*)l)[1];
    }
    // ---- stage B (32 x BN fp32 -> split bf16, transposed to [n][k]) ----
    {
      alignas(16) short h[KPER], l[KPER];
#pragma unroll
      for (int i = 0; i < KPER; ++i) {
        float v = B[(size_t)(k0 + kb + i) * Nn + colBase + nb];
        split2(v, h[i], l[i]);
      }
#pragma unroll
      for (int i = 0; i < KPER / 8; ++i) {
        *(bf16x8*)&Bh[nb][kb + i * 8] = ((bf16x8*)h)[i];
        *(bf16x8*)&Bl[nb][kb + i * 8] = ((bf16x8*)l)[i];
      }
    }
    __syncthreads();
    // ---- fragments + MFMA ----
    bf16x8 afh[MT], afl[MT], bfh[NT], bfl[NT];
#pragma unroll
    for (int mt = 0; mt < MT; ++mt) {
      afh[mt] = *(const bf16x8*)&Ah[wm + mt * 16 + l16][quad * 8];
      afl[mt] = *(const bf16x8*)&Al[wm + mt * 16 + l16][quad * 8];
    }
#pragma unroll
    for (int nt = 0; nt < NT; ++nt) {
      bfh[nt] = *(const bf16x8*)&Bh[wn + nt * 16 + l16][quad * 8];
      bfl[nt] = *(const bf16x8*)&Bl[wn + nt * 16 + l16][quad * 8];
    }
#pragma unroll
    for (int mt = 0; mt < MT; ++mt)
#pragma unroll
      for (int nt = 0; nt < NT; ++nt) {
        acc[mt][nt] = __builtin_amdgcn_mfma_f32_16x16x32_bf16(afh[mt], bfh[nt], acc[mt][nt], 0, 0, 0);
        acc[mt][nt] = __builtin_amdgcn_mfma_f32_16x16x32_bf16(afh[mt], bfl[nt], acc[mt][nt], 0, 0, 0);
        acc[mt][nt] = __builtin_amdgcn_mfma_f32_16x16x32_bf16(afl[mt], bfh[nt], acc[mt][nt], 0, 0, 0);
      }
    __syncthreads();
  }
  // ---- epilogue: C/D layout col=lane&15, row=quad*4+reg ----
#pragma unroll
  for (int mt = 0; mt < MT; ++mt) {
    int r0 = rowBase + wm + mt * 16 + quad * 4;
#pragma unroll
    for (int nt = 0; nt < NT; ++nt) {
      int c = colBase + wn + nt * 16 + l16;
#pragma unroll
      for (int reg = 0; reg < 4; ++reg) {
        int r = r0 + reg;
        if (r < M) C[(size_t)r * Nn + c] = acc[mt][nt][reg];
      }
    }
  }
}

// ============================================================
// attention dot products
// ============================================================
__global__ __launch_bounds__(256) void attdot4(
    const float* __restrict__ h1, const float* __restrict__ att_src,
    const float* __restrict__ att_dst, float* __restrict__ a_src,
    float* __restrict__ a_dst, int n) {
  int node = blockIdx.x * 4 + (threadIdx.x >> 6);
  int lane = threadIdx.x & 63;
  if (node >= n) return;
  const float* hrow = h1 + (size_t)node * 256;
#pragma unroll
  for (int h = 0; h < 4; ++h) {
    float v = hrow[h * 64 + lane];
    float s = v * att_src[h * 64 + lane];
    float d = v * att_dst[h * 64 + lane];
#pragma unroll
    for (int off = 32; off > 0; off >>= 1) {
      s += __shfl_xor(s, off);
      d += __shfl_xor(d, off);
    }
    if (lane == 0) {
      a_src[node * 4 + h] = s;
      a_dst[node * 4 + h] = d;
    }
  }
}

__global__ __launch_bounds__(256) void attdot1h(
    const float* __restrict__ h2, const float* __restrict__ att_src,
    const float* __restrict__ att_dst, float* __restrict__ a_src,
    float* __restrict__ a_dst, int n) {
  int node = blockIdx.x * 4 + (threadIdx.x >> 6);
  int lane = threadIdx.x & 63;
  if (node >= n) return;
  float v = h2[(size_t)node * 64 + lane];
  float s = v * att_src[lane];
  float d = v * att_dst[lane];
#pragma unroll
  for (int off = 32; off > 0; off >>= 1) {
    s += __shfl_xor(s, off);
    d += __shfl_xor(d, off);
  }
  if (lane == 0) {
    a_src[node] = s;
    a_dst[node] = d;
  }
}

// ============================================================
// Fused softmax + aggregation, layer 1 (H=4, C=64)
// ============================================================
__global__ __launch_bounds__(256) void agg_l1(
    const int* __restrict__ offs, const int* __restrict__ ssort,
    const float* __restrict__ asrc, const float* __restrict__ adst,
    const float* __restrict__ h1, const float* __restrict__ b1,
    float* __restrict__ outp) {
  const int d = blockIdx.x;
  const int t = threadIdx.x;
  const int h = t >> 6;
  __shared__ int s_src[256];
  __shared__ float s_sc[256 * 4];
  __shared__ float s_m[4];
  const int row0 = offs[d], row1 = offs[d + 1];
  const float4 ad4 = *(const float4*)&adst[d * 4];
  float m = -INFINITY, acc = 0.f, denom = 0.f;

  for (int j0 = row0; j0 < row1; j0 += 256) {
    const int n = min(256, row1 - j0);
    if (t < n) {
      int s = ssort[j0 + t];
      s_src[t] = s;
      float4 as = *(const float4*)&asrc[s * 4];
      float4 sc;
      sc.x = as.x + ad4.x; sc.x = sc.x > 0.f ? sc.x : 0.2f * sc.x;
      sc.y = as.y + ad4.y; sc.y = sc.y > 0.f ? sc.y : 0.2f * sc.y;
      sc.z = as.z + ad4.z; sc.z = sc.z > 0.f ? sc.z : 0.2f * sc.z;
      sc.w = as.w + ad4.w; sc.w = sc.w > 0.f ? sc.w : 0.2f * sc.w;
      *(float4*)&s_sc[t * 4] = sc;
    }
    __syncthreads();
    float mc = -INFINITY;
    for (int j = 0; j < n; ++j) mc = fmaxf(mc, s_sc[j * 4 + h]);
    float mn = fmaxf(m, mc);
    float scale = expf(m - mn);
    acc *= scale;
    denom *= scale;
    m = mn;
    if ((t & 63) == 0) s_m[h] = mn;
    __syncthreads();
    for (int j = t; j < n * 4; j += 256)
      s_sc[j] = expf(s_sc[j] - s_m[j & 3]);
    __syncthreads();
    for (int j = 0; j < n; ++j) {
      float exv = s_sc[j * 4 + h];
      denom += exv;
      acc += h1[(size_t)s_src[j] * 256 + t] * exv;
    }
    __syncthreads();
  }
  float val = (denom > 0.f ? acc / denom : 0.f) + b1[t];
  outp[(size_t)d * 256 + t] = val > 0.f ? val : expm1f(val);
}

// ============================================================
// Fused softmax + aggregation, layer 2 (H=1, C=64)
// ============================================================
__global__ __launch_bounds__(256) void agg_l2(
    const int* __restrict__ offs, const int* __restrict__ ssort,
    const float* __restrict__ asrc, const float* __restrict__ adst,
    const float* __restrict__ h2, const float* __restrict__ b2,
    float* __restrict__ outp, int n_nodes) {
  int d = blockIdx.x * 4 + (threadIdx.x >> 6);
  int lane = threadIdx.x & 63;
  if (d >= n_nodes) return;
  const int row0 = offs[d], row1 = offs[d + 1];
  const float ad = adst[d];
  float m = -INFINITY, acc = 0.f, denom = 0.f;

  for (int j0 = row0; j0 < row1; j0 += 64) {
    const int n = min(64, row1 - j0);
    int s = 0;
    float sc = -INFINITY;
    if (lane < n) {
      s = ssort[j0 + lane];
      sc = asrc[s] + ad;
      sc = sc > 0.f ? sc : 0.2f * sc;
    }
    float mc = sc;
#pragma unroll
    for (int off = 32; off > 0; off >>= 1) mc = fmaxf(mc, __shfl_xor(mc, off));
    float mn = fmaxf(m, mc);
    float scale = expf(m - mn);
    acc *= scale;
    denom *= scale;
    m = mn;
    float ex = (lane < n) ? expf(sc - mn) : 0.f;
    float ds = ex;
#pragma unroll
    for (int off = 32; off > 0; off >>= 1) ds += __shfl_xor(ds, off);
    denom += ds;
    for (int j = 0; j < n; ++j) {
      int sj = __shfl(s, j);
      float exj = __shfl(ex, j);
      acc += h2[(size_t)sj * 64 + lane] * exj;
    }
  }
  float val = (denom > 0.f ? acc / denom : 0.f) + b2[lane];
  outp[(size_t)d * 64 + lane] = val;
}

// ============================================================
// final MLP head
// ============================================================
__global__ __launch_bounds__(256) void mlp_head(
    const float* __restrict__ emb_in,
    const float* __restrict__ mw1, const float* __restrict__ mb1,
    const float* __restrict__ mw2, const float* __restrict__ mb2,
    float* __restrict__ outp, int n) {
  __shared__ float w1s[64 * 64];
  __shared__ float w2s[64 * 40];
  __shared__ float b1s[64];
  __shared__ float b2s[40];
  int t = threadIdx.x;
  for (int i = t; i < 64 * 64; i += 256) w1s[i] = mw1[i];
  for (int i = t; i < 64 * 40; i += 256) w2s[i] = mw2[i];
  if (t < 64) b1s[t] = mb1[t];
  if (t < 40) b2s[t] = mb2[t];
  __syncthreads();
  int node = blockIdx.x * 256 + t;
  if (node >= n) return;
  float emb[64];
#pragma unroll
  for (int i = 0; i < 64; ++i) emb[i] = emb_in[(size_t)node * 64 + i];
  float hid[64];
#pragma unroll
  for (int j = 0; j < 64; ++j) {
    float s = b1s[j];
#pragma unroll
    for (int i = 0; i < 64; ++i) s += emb[i] * w1s[i * 64 + j];
    hid[j] = s > 0.f ? s : 0.f;
  }
#pragma unroll
  for (int k = 0; k < 40; ++k) {
    float s = b2s[k];
#pragma unroll
    for (int j = 0; j < 64; ++j) s += hid[j] * w2s[j * 40 + k];
    outp[(size_t)node * 40 + k] = s;
  }
}

extern "C" void kernel_launch(void* const* d_in, const int* in_sizes, int n_in,
                              void* d_out, int out_size, void* d_ws, size_t ws_size,
                              hipStream_t stream) {
  const float* x        = (const float*)d_in[0];
  const int*   ei       = (const int*)d_in[1];
  const float* W1       = (const float*)d_in[2];
  const float* att_src1 = (const float*)d_in[3];
  const float* att_dst1 = (const float*)d_in[4];
  const float* b1       = (const float*)d_in[5];
  const float* W2       = (const float*)d_in[6];
  const float* att_src2 = (const float*)d_in[7];
  const float* att_dst2 = (const float*)d_in[8];
  const float* b2       = (const float*)d_in[9];
  const float* mw1      = (const float*)d_in[10];
  const float* mb1      = (const float*)d_in[11];
  const float* mw2      = (const float*)d_in[12];
  const float* mb2      = (const float*)d_in[13];
  float* out = (float*)d_out;

  const int N = N_NODES, E = N_EDGES;
  char* base = (char*)d_ws;
  size_t o = 0;
  auto alloc = [&](size_t n_elems) {
    void* p = base + o;
    o += n_elems * 4;
    return p;
  };
  int* cnt = (int*)alloc(N);
  int* cur = (int*)alloc(N);
  size_t zero_bytes = o;
  int*   offs  = (int*)alloc(N + 2);
  int*   bsum  = (int*)alloc(256);
  int*   bofs  = (int*)alloc(256);
  int*   ssort = (int*)alloc(E);
  float* h1    = (float*)alloc((size_t)N * 256);
  float* h1e   = (float*)alloc((size_t)N * 256);
  float* asrc1 = (float*)alloc((size_t)N * 4);
  float* adst1 = (float*)alloc((size_t)N * 4);
  float* h2    = (float*)alloc((size_t)N * 64);
  float* emb   = (float*)alloc((size_t)N * 64);
  float* asrc2 = (float*)alloc(N);
  float* adst2 = (float*)alloc(N);

  hipMemsetAsync(d_ws, 0, zero_bytes, stream);

  const int EB = (E + 255) / 256;

  // ---- build dst-sorted CSR (shared by both layers) ----
  hist_k<<<EB, 256, 0, stream>>>(ei, cnt);
  scan1<<<SCAN_B, 256, 0, stream>>>(cnt, offs, bsum);
  scan2<<<1, 256, 0, stream>>>(bsum, bofs);
  scan3<<<SCAN_B, 256, 0, stream>>>(offs, bofs);
  scatter_k<<<EB, 256, 0, stream>>>(ei, offs, cur, ssort);

  // ---- layer 1 ----
  dim3 g1((N + 127) / 128, 256 / 128);
  gemm_mfma<128, 2, 2><<<g1, 256, 0, stream>>>(x, W1, h1, N, 256, 512);
  attdot4<<<(N + 3) / 4, 256, 0, stream>>>(h1, att_src1, att_dst1, asrc1, adst1, N);
  agg_l1<<<N, 256, 0, stream>>>(offs, ssort, asrc1, adst1, h1, b1, h1e);

  // ---- layer 2 ----
  dim3 g2((N + 127) / 128, 1);
  gemm_mfma<64, 4, 1><<<g2, 256, 0, stream>>>(h1e, W2, h2, N, 64, 256);
  attdot1h<<<(N + 3) / 4, 256, 0, stream>>>(h2, att_src2, att_dst2, asrc2, adst2, N);
  agg_l2<<<(N + 3) / 4, 256, 0, stream>>>(offs, ssort, asrc2, adst2, h2, b2, emb, N);

  // ---- MLP head ----
  mlp_head<<<(N + 255) / 256, 256, 0, stream>>>(emb, mw1, mb1, mw2, mb2, out, N);
}

// Round 4
// 562.485 us; speedup vs baseline: 3.0562x; 1.1087x over previous
//
#include <hip/hip_runtime.h>

#define N_NODES 50000
#define N_EDGES 800000
#define SCAN_B 196   // ceil(50000/256)

typedef short bf16x8 __attribute__((ext_vector_type(8)));
typedef float f32x4 __attribute__((ext_vector_type(4)));

__device__ __forceinline__ unsigned short f2bf_rne(float x) {
  unsigned u = __float_as_uint(x);
  u += 0x7FFFu + ((u >> 16) & 1u);
  return (unsigned short)(u >> 16);
}

// ============================================================
// Counting sort by dst: hist -> 2-level exclusive scan -> scatter
// ============================================================
__global__ __launch_bounds__(256) void hist_k(const int* __restrict__ ei,
                                              int* __restrict__ cnt) {
  int e = blockIdx.x * 256 + threadIdx.x;
  if (e >= N_EDGES) return;
  atomicAdd(&cnt[ei[N_EDGES + e]], 1);
}

__global__ __launch_bounds__(256) void scan1(const int* __restrict__ cnt,
                                             int* __restrict__ offs,
                                             int* __restrict__ bsum) {
  __shared__ int sh[256];
  int t = threadIdx.x;
  int i = blockIdx.x * 256 + t;
  int v = (i < N_NODES) ? cnt[i] : 0;
  sh[t] = v;
  __syncthreads();
  for (int off = 1; off < 256; off <<= 1) {
    int add = (t >= off) ? sh[t - off] : 0;
    __syncthreads();
    sh[t] += add;
    __syncthreads();
  }
  if (i < N_NODES) offs[i] = sh[t] - v;  // exclusive
  if (t == 255) bsum[blockIdx.x] = sh[255];
}

__global__ __launch_bounds__(256) void scan2(const int* __restrict__ bsum,
                                             int* __restrict__ bofs) {
  __shared__ int sh[256];
  int t = threadIdx.x;
  int v = (t < SCAN_B) ? bsum[t] : 0;
  sh[t] = v;
  __syncthreads();
  for (int off = 1; off < 256; off <<= 1) {
    int add = (t >= off) ? sh[t - off] : 0;
    __syncthreads();
    sh[t] += add;
    __syncthreads();
  }
  if (t < SCAN_B) bofs[t] = sh[t] - v;
}

__global__ __launch_bounds__(256) void scan3(int* __restrict__ offs,
                                             const int* __restrict__ bofs) {
  int i = blockIdx.x * 256 + threadIdx.x;
  if (i < N_NODES) offs[i] += bofs[blockIdx.x];
  if (i == 0) offs[N_NODES] = N_EDGES;
}

__global__ __launch_bounds__(256) void scatter_k(const int* __restrict__ ei,
                                                 const int* __restrict__ offs,
                                                 int* __restrict__ cur,
                                                 int* __restrict__ ssort) {
  int e = blockIdx.x * 256 + threadIdx.x;
  if (e >= N_EDGES) return;
  int d = ei[N_EDGES + e];
  int p = offs[d] + atomicAdd(&cur[d], 1);
  ssort[p] = ei[e];
}

// ============================================================
// fp32 GEMM via split-bf16 MFMA (3-pass hi/lo emulation).
// Optionally also writes an RNE-bf16 copy of C (Cb != nullptr).
// ============================================================
__device__ __forceinline__ void split2(float x, short& hi, short& lo) {
  unsigned u = __float_as_uint(x);
  unsigned short h = (unsigned short)(u >> 16);  // truncate to bf16
  float hf = __uint_as_float((unsigned)h << 16);
  float r = x - hf;
  unsigned short l = (unsigned short)(__float_as_uint(r) >> 16);
  hi = (short)h;
  lo = (short)l;
}

template <int BN, int WGM, int WGN>
__global__ __launch_bounds__(256) void gemm_mfma(
    const float* __restrict__ A, const float* __restrict__ B,
    float* __restrict__ C, unsigned short* __restrict__ Cb,
    int M, int Nn, int K) {
  constexpr int BM = 128;
  constexpr int WM = BM / WGM;
  constexpr int WN = BN / WGN;
  constexpr int MT = WM / 16;
  constexpr int NT = WN / 16;
  constexpr int LDA = 40;
  constexpr int KPER = BN / 8;

  __shared__ short Ah[BM][LDA], Al[BM][LDA];
  __shared__ short Bh[BN][LDA], Bl[BN][LDA];

  const int tid = threadIdx.x;
  const int wave = tid >> 6;
  const int lane = tid & 63;
  const int quad = lane >> 4;
  const int l16 = lane & 15;
  const int wm = (wave / WGN) * WM;
  const int wn = (wave % WGN) * WN;
  const int rowBase = blockIdx.x * BM;
  const int colBase = blockIdx.y * BN;

  const int ra = tid >> 1;
  const int apart = (tid & 1) * 16;
  const int nb = tid & (BN - 1);
  const int kb = (tid / BN) * KPER;

  const int arow = min(rowBase + ra, M - 1);
  const float* aptr = A + (size_t)arow * K + apart;

  f32x4 acc[MT][NT] = {};

  for (int k0 = 0; k0 < K; k0 += 32) {
    {
      alignas(16) short h[16], l[16];
      const float4* a4 = (const float4*)(aptr + k0);
#pragma unroll
      for (int i = 0; i < 4; ++i) {
        float4 v = a4[i];
        split2(v.x, h[i * 4 + 0], l[i * 4 + 0]);
        split2(v.y, h[i * 4 + 1], l[i * 4 + 1]);
        split2(v.z, h[i * 4 + 2], l[i * 4 + 2]);
        split2(v.w, h[i * 4 + 3], l[i * 4 + 3]);
      }
      *(bf16x8*)&Ah[ra][apart]     = ((bf16x8*)h)[0];
      *(bf16x8*)&Ah[ra][apart + 8] = ((bf16x8*)h)[1];
      *(bf16x8*)&Al[ra][apart]     = ((bf16x8*)l)[0];
      *(bf16x8*)&Al[ra][apart + 8] = ((bf16x8*)l)[1];
    }
    {
      alignas(16) short h[KPER], l[KPER];
#pragma unroll
      for (int i = 0; i < KPER; ++i) {
        float v = B[(size_t)(k0 + kb + i) * Nn + colBase + nb];
        split2(v, h[i], l[i]);
      }
#pragma unroll
      for (int i = 0; i < KPER / 8; ++i) {
        *(bf16x8*)&Bh[nb][kb + i * 8] = ((bf16x8*)h)[i];
        *(bf16x8*)&Bl[nb][kb + i * 8] = ((bf16x8*)l)[i];
      }
    }
    __syncthreads();
    bf16x8 afh[MT], afl[MT], bfh[NT], bfl[NT];
#pragma unroll
    for (int mt = 0; mt < MT; ++mt) {
      afh[mt] = *(const bf16x8*)&Ah[wm + mt * 16 + l16][quad * 8];
      afl[mt] = *(const bf16x8*)&Al[wm + mt * 16 + l16][quad * 8];
    }
#pragma unroll
    for (int nt = 0; nt < NT; ++nt) {
      bfh[nt] = *(const bf16x8*)&Bh[wn + nt * 16 + l16][quad * 8];
      bfl[nt] = *(const bf16x8*)&Bl[wn + nt * 16 + l16][quad * 8];
    }
#pragma unroll
    for (int mt = 0; mt < MT; ++mt)
#pragma unroll
      for (int nt = 0; nt < NT; ++nt) {
        acc[mt][nt] = __builtin_amdgcn_mfma_f32_16x16x32_bf16(afh[mt], bfh[nt], acc[mt][nt], 0, 0, 0);
        acc[mt][nt] = __builtin_amdgcn_mfma_f32_16x16x32_bf16(afh[mt], bfl[nt], acc[mt][nt], 0, 0, 0);
        acc[mt][nt] = __builtin_amdgcn_mfma_f32_16x16x32_bf16(afl[mt], bfh[nt], acc[mt][nt], 0, 0, 0);
      }
    __syncthreads();
  }
#pragma unroll
  for (int mt = 0; mt < MT; ++mt) {
    int r0 = rowBase + wm + mt * 16 + quad * 4;
#pragma unroll
    for (int nt = 0; nt < NT; ++nt) {
      int c = colBase + wn + nt * 16 + l16;
#pragma unroll
      for (int reg = 0; reg < 4; ++reg) {
        int r = r0 + reg;
        if (r < M) {
          float v = acc[mt][nt][reg];
          C[(size_t)r * Nn + c] = v;
          if (Cb) Cb[(size_t)r * Nn + c] = f2bf_rne(v);
        }
      }
    }
  }
}

// ============================================================
// attention dot products (fp32 inputs, exact)
// ============================================================
__global__ __launch_bounds__(256) void attdot4(
    const float* __restrict__ h1, const float* __restrict__ att_src,
    const float* __restrict__ att_dst, float* __restrict__ a_src,
    float* __restrict__ a_dst, int n) {
  int node = blockIdx.x * 4 + (threadIdx.x >> 6);
  int lane = threadIdx.x & 63;
  if (node >= n) return;
  const float* hrow = h1 + (size_t)node * 256;
#pragma unroll
  for (int h = 0; h < 4; ++h) {
    float v = hrow[h * 64 + lane];
    float s = v * att_src[h * 64 + lane];
    float d = v * att_dst[h * 64 + lane];
#pragma unroll
    for (int off = 32; off > 0; off >>= 1) {
      s += __shfl_xor(s, off);
      d += __shfl_xor(d, off);
    }
    if (lane == 0) {
      a_src[node * 4 + h] = s;
      a_dst[node * 4 + h] = d;
    }
  }
}

__global__ __launch_bounds__(256) void attdot1h(
    const float* __restrict__ h2, const float* __restrict__ att_src,
    const float* __restrict__ att_dst, float* __restrict__ a_src,
    float* __restrict__ a_dst, int n) {
  int node = blockIdx.x * 4 + (threadIdx.x >> 6);
  int lane = threadIdx.x & 63;
  if (node >= n) return;
  float v = h2[(size_t)node * 64 + lane];
  float s = v * att_src[lane];
  float d = v * att_dst[lane];
#pragma unroll
  for (int off = 32; off > 0; off >>= 1) {
    s += __shfl_xor(s, off);
    d += __shfl_xor(d, off);
  }
  if (lane == 0) {
    a_src[node] = s;
    a_dst[node] = d;
  }
}

// ============================================================
// Fused softmax + aggregation, layer 1 (H=4, C=64).
// 128 threads per dst node; thread owns a bf16 feature PAIR.
// No max subtraction (scores O(1), overflow-free); exp fused in staging.
// ============================================================
__global__ __launch_bounds__(128) void agg_l1(
    const int* __restrict__ offs, const int* __restrict__ ssort,
    const float* __restrict__ asrc, const float* __restrict__ adst,
    const unsigned short* __restrict__ h1b, const float* __restrict__ b1,
    float* __restrict__ outp) {
  const int d = blockIdx.x;
  const int t = threadIdx.x;       // 0..127; features 2t, 2t+1
  const int h = t >> 5;            // head 0..3
  __shared__ int s_src[128];
  __shared__ float s_ex[128 * 4];
  const int row0 = offs[d], row1 = offs[d + 1];
  const float4 ad4 = *(const float4*)&adst[d * 4];
  float acc0 = 0.f, acc1 = 0.f, denom = 0.f;

  for (int j0 = row0; j0 < row1; j0 += 128) {
    const int n = min(128, row1 - j0);
    if (t < n) {
      int s = ssort[j0 + t];
      s_src[t] = s;
      float4 as = *(const float4*)&asrc[s * 4];
      float4 sc;
      sc.x = as.x + ad4.x; sc.x = sc.x > 0.f ? sc.x : 0.2f * sc.x;
      sc.y = as.y + ad4.y; sc.y = sc.y > 0.f ? sc.y : 0.2f * sc.y;
      sc.z = as.z + ad4.z; sc.z = sc.z > 0.f ? sc.z : 0.2f * sc.z;
      sc.w = as.w + ad4.w; sc.w = sc.w > 0.f ? sc.w : 0.2f * sc.w;
      sc.x = __expf(sc.x); sc.y = __expf(sc.y);
      sc.z = __expf(sc.z); sc.w = __expf(sc.w);
      *(float4*)&s_ex[t * 4] = sc;
    }
    __syncthreads();
    for (int j = 0; j < n; ++j) {
      float exv = s_ex[j * 4 + h];
      unsigned pv = *(const unsigned*)&h1b[(size_t)s_src[j] * 256 + 2 * t];
      float f0 = __uint_as_float(pv << 16);
      float f1 = __uint_as_float(pv & 0xFFFF0000u);
      acc0 += f0 * exv;
      acc1 += f1 * exv;
      denom += exv;
    }
    __syncthreads();
  }
  float inv = denom > 0.f ? 1.f / denom : 0.f;
  float v0 = acc0 * inv + b1[2 * t];
  float v1 = acc1 * inv + b1[2 * t + 1];
  float2 r;
  r.x = v0 > 0.f ? v0 : expm1f(v0);
  r.y = v1 > 0.f ? v1 : expm1f(v1);
  *(float2*)&outp[(size_t)d * 256 + 2 * t] = r;
}

// ============================================================
// Fused softmax + aggregation, layer 2 (H=1, C=64), bf16 gather, no max.
// ============================================================
__global__ __launch_bounds__(256) void agg_l2(
    const int* __restrict__ offs, const int* __restrict__ ssort,
    const float* __restrict__ asrc, const float* __restrict__ adst,
    const unsigned short* __restrict__ h2b, const float* __restrict__ b2,
    float* __restrict__ outp, int n_nodes) {
  int d = blockIdx.x * 4 + (threadIdx.x >> 6);
  int lane = threadIdx.x & 63;
  if (d >= n_nodes) return;
  const int row0 = offs[d], row1 = offs[d + 1];
  const float ad = adst[d];
  float acc = 0.f, denom = 0.f;

  for (int j0 = row0; j0 < row1; j0 += 64) {
    const int n = min(64, row1 - j0);
    int s = 0;
    float ex = 0.f;
    if (lane < n) {
      s = ssort[j0 + lane];
      float sc = asrc[s] + ad;
      sc = sc > 0.f ? sc : 0.2f * sc;
      ex = __expf(sc);
    }
    float ds = ex;
#pragma unroll
    for (int off = 32; off > 0; off >>= 1) ds += __shfl_xor(ds, off);
    denom += ds;
    for (int j = 0; j < n; ++j) {
      int sj = __shfl(s, j);
      float exj = __shfl(ex, j);
      float f = __uint_as_float((unsigned)h2b[(size_t)sj * 64 + lane] << 16);
      acc += f * exj;
    }
  }
  float val = (denom > 0.f ? acc / denom : 0.f) + b2[lane];
  outp[(size_t)d * 64 + lane] = val;
}

// ============================================================
// final MLP head
// ============================================================
__global__ __launch_bounds__(256) void mlp_head(
    const float* __restrict__ emb_in,
    const float* __restrict__ mw1, const float* __restrict__ mb1,
    const float* __restrict__ mw2, const float* __restrict__ mb2,
    float* __restrict__ outp, int n) {
  __shared__ float w1s[64 * 64];
  __shared__ float w2s[64 * 40];
  __shared__ float b1s[64];
  __shared__ float b2s[40];
  int t = threadIdx.x;
  for (int i = t; i < 64 * 64; i += 256) w1s[i] = mw1[i];
  for (int i = t; i < 64 * 40; i += 256) w2s[i] = mw2[i];
  if (t < 64) b1s[t] = mb1[t];
  if (t < 40) b2s[t] = mb2[t];
  __syncthreads();
  int node = blockIdx.x * 256 + t;
  if (node >= n) return;
  float emb[64];
#pragma unroll
  for (int i = 0; i < 64; ++i) emb[i] = emb_in[(size_t)node * 64 + i];
  float hid[64];
#pragma unroll
  for (int j = 0; j < 64; ++j) {
    float s = b1s[j];
#pragma unroll
    for (int i = 0; i < 64; ++i) s += emb[i] * w1s[i * 64 + j];
    hid[j] = s > 0.f ? s : 0.f;
  }
#pragma unroll
  for (int k = 0; k < 40; ++k) {
    float s = b2s[k];
#pragma unroll
    for (int j = 0; j < 64; ++j) s += hid[j] * w2s[j * 40 + k];
    outp[(size_t)node * 40 + k] = s;
  }
}

extern "C" void kernel_launch(void* const* d_in, const int* in_sizes, int n_in,
                              void* d_out, int out_size, void* d_ws, size_t ws_size,
                              hipStream_t stream) {
  const float* x        = (const float*)d_in[0];
  const int*   ei       = (const int*)d_in[1];
  const float* W1       = (const float*)d_in[2];
  const float* att_src1 = (const float*)d_in[3];
  const float* att_dst1 = (const float*)d_in[4];
  const float* b1       = (const float*)d_in[5];
  const float* W2       = (const float*)d_in[6];
  const float* att_src2 = (const float*)d_in[7];
  const float* att_dst2 = (const float*)d_in[8];
  const float* b2       = (const float*)d_in[9];
  const float* mw1      = (const float*)d_in[10];
  const float* mb1      = (const float*)d_in[11];
  const float* mw2      = (const float*)d_in[12];
  const float* mb2      = (const float*)d_in[13];
  float* out = (float*)d_out;

  const int N = N_NODES, E = N_EDGES;
  char* base = (char*)d_ws;
  size_t o = 0;
  auto alloc = [&](size_t n_elems) {
    void* p = base + o;
    o += n_elems * 4;
    return p;
  };
  int* cnt = (int*)alloc(N);
  int* cur = (int*)alloc(N);
  size_t zero_bytes = o;
  int*   offs  = (int*)alloc(N + 2);
  int*   bsum  = (int*)alloc(256);
  int*   bofs  = (int*)alloc(256);
  int*   ssort = (int*)alloc(E);
  float* h1    = (float*)alloc((size_t)N * 256);
  float* h1e   = (float*)alloc((size_t)N * 256);
  float* asrc1 = (float*)alloc((size_t)N * 4);
  float* adst1 = (float*)alloc((size_t)N * 4);
  float* h2    = (float*)alloc((size_t)N * 64);
  float* emb   = (float*)alloc((size_t)N * 64);
  float* asrc2 = (float*)alloc(N);
  float* adst2 = (float*)alloc(N);
  unsigned short* h1b = (unsigned short*)alloc((size_t)N * 128);  // N*256 ushorts
  unsigned short* h2b = (unsigned short*)alloc((size_t)N * 32);   // N*64 ushorts

  hipMemsetAsync(d_ws, 0, zero_bytes, stream);

  const int EB = (E + 255) / 256;

  // ---- build dst-sorted CSR (shared by both layers) ----
  hist_k<<<EB, 256, 0, stream>>>(ei, cnt);
  scan1<<<SCAN_B, 256, 0, stream>>>(cnt, offs, bsum);
  scan2<<<1, 256, 0, stream>>>(bsum, bofs);
  scan3<<<SCAN_B, 256, 0, stream>>>(offs, bofs);
  scatter_k<<<EB, 256, 0, stream>>>(ei, offs, cur, ssort);

  // ---- layer 1 ----
  dim3 g1((N + 127) / 128, 256 / 128);
  gemm_mfma<128, 2, 2><<<g1, 256, 0, stream>>>(x, W1, h1, h1b, N, 256, 512);
  attdot4<<<(N + 3) / 4, 256, 0, stream>>>(h1, att_src1, att_dst1, asrc1, adst1, N);
  agg_l1<<<N, 128, 0, stream>>>(offs, ssort, asrc1, adst1, h1b, b1, h1e);

  // ---- layer 2 ----
  dim3 g2((N + 127) / 128, 1);
  gemm_mfma<64, 4, 1><<<g2, 256, 0, stream>>>(h1e, W2, h2, h2b, N, 64, 256);
  attdot1h<<<(N + 3) / 4, 256, 0, stream>>>(h2, att_src2, att_dst2, asrc2, adst2, N);
  agg_l2<<<(N + 3) / 4, 256, 0, stream>>>(offs, ssort, asrc2, adst2, h2b, b2, emb, N);

  // ---- MLP head ----
  mlp_head<<<(N + 255) / 256, 256, 0, stream>>>(emb, mw1, mb1, mw2, mb2, out, N);
}

// Round 5
// 512.012 us; speedup vs baseline: 3.3574x; 1.0986x over previous
//
#include <hip/hip_runtime.h>

#define N_NODES 50000
#define N_EDGES 800000
#define SCAN_B 196   // ceil(50000/256)

typedef short bf16x8 __attribute__((ext_vector_type(8)));
typedef float f32x4 __attribute__((ext_vector_type(4)));

#define GLDS16(g, l)                                                  \
  __builtin_amdgcn_global_load_lds(                                   \
      (const __attribute__((address_space(1))) void*)(g),             \
      (__attribute__((address_space(3))) void*)(l), 16, 0, 0)

__device__ __forceinline__ unsigned short f2bf_rne(float x) {
  unsigned u = __float_as_uint(x);
  u += 0x7FFFu + ((u >> 16) & 1u);
  return (unsigned short)(u >> 16);
}

__device__ __forceinline__ void split2(float x, short& hi, short& lo) {
  unsigned u = __float_as_uint(x);
  unsigned short h = (unsigned short)(u >> 16);  // truncate to bf16
  float hf = __uint_as_float((unsigned)h << 16);
  float r = x - hf;
  unsigned short l = (unsigned short)(__float_as_uint(r) >> 16);
  hi = (short)h;
  lo = (short)l;
}

// ============================================================
// Counting sort by dst: hist -> 2-level exclusive scan -> scatter
// ============================================================
__global__ __launch_bounds__(256) void hist_k(const int* __restrict__ ei,
                                              int* __restrict__ cnt) {
  int e = blockIdx.x * 256 + threadIdx.x;
  if (e >= N_EDGES) return;
  atomicAdd(&cnt[ei[N_EDGES + e]], 1);
}

__global__ __launch_bounds__(256) void scan1(const int* __restrict__ cnt,
                                             int* __restrict__ offs,
                                             int* __restrict__ bsum) {
  __shared__ int sh[256];
  int t = threadIdx.x;
  int i = blockIdx.x * 256 + t;
  int v = (i < N_NODES) ? cnt[i] : 0;
  sh[t] = v;
  __syncthreads();
  for (int off = 1; off < 256; off <<= 1) {
    int add = (t >= off) ? sh[t - off] : 0;
    __syncthreads();
    sh[t] += add;
    __syncthreads();
  }
  if (i < N_NODES) offs[i] = sh[t] - v;  // exclusive
  if (t == 255) bsum[blockIdx.x] = sh[255];
}

__global__ __launch_bounds__(256) void scan2(const int* __restrict__ bsum,
                                             int* __restrict__ bofs) {
  __shared__ int sh[256];
  int t = threadIdx.x;
  int v = (t < SCAN_B) ? bsum[t] : 0;
  sh[t] = v;
  __syncthreads();
  for (int off = 1; off < 256; off <<= 1) {
    int add = (t >= off) ? sh[t - off] : 0;
    __syncthreads();
    sh[t] += add;
    __syncthreads();
  }
  if (t < SCAN_B) bofs[t] = sh[t] - v;
}

__global__ __launch_bounds__(256) void scan3(int* __restrict__ offs,
                                             const int* __restrict__ bofs) {
  int i = blockIdx.x * 256 + threadIdx.x;
  if (i < N_NODES) offs[i] += bofs[blockIdx.x];
  if (i == 0) offs[N_NODES] = N_EDGES;
}

__global__ __launch_bounds__(256) void scatter_k(const int* __restrict__ ei,
                                                 const int* __restrict__ offs,
                                                 int* __restrict__ cur,
                                                 int* __restrict__ ssort) {
  int e = blockIdx.x * 256 + threadIdx.x;
  if (e >= N_EDGES) return;
  int d = ei[N_EDGES + e];
  int p = offs[d] + atomicAdd(&cur[d], 1);
  ssort[p] = ei[e];
}

// ============================================================
// Pre-split weights into bf16 hi/lo, MFMA-fragment layout:
// chunk (kc, quad, n)[j] = W[(kc*32+quad*8+j)*Nn + n]
// ============================================================
__global__ __launch_bounds__(256) void wsplit(
    const float* __restrict__ W, unsigned short* __restrict__ Wh,
    unsigned short* __restrict__ Wl, int K, int Nn) {
  int i = blockIdx.x * 256 + threadIdx.x;   // chunk id
  int total = (K >> 3) * Nn;
  if (i >= total) return;
  int kq = i / Nn;          // k-group of 8
  int n = i % Nn;
  alignas(16) short h[8], l[8];
#pragma unroll
  for (int j = 0; j < 8; ++j) {
    float v = W[(size_t)(kq * 8 + j) * Nn + n];
    split2(v, h[j], l[j]);
  }
  size_t dst = (size_t)i * 8;  // (kc*4+quad)*Nn + n == kq*Nn + n ... careful:
  // chunk order must be [kc][quad][n]: kq = kc*4+quad, so chunk index
  // (kc*4+quad)*Nn + n = kq*Nn + n == i  ✓
  *(bf16x8*)&Wh[dst] = *(bf16x8*)h;
  *(bf16x8*)&Wl[dst] = *(bf16x8*)l;
}

// ============================================================
// GEMM1 fused: h1b = bf16(x @ W1), asrc/adst = att dots (fp32, exact).
// BM=128, BN=128 (grid.y=2 column tiles, each = 2 complete heads).
// A: fp32 load + split in-register -> padded LDS.
// B: pre-split fragment-layout, staged via global_load_lds.
// ============================================================
__global__ __launch_bounds__(256) void gemm1_fused(
    const float* __restrict__ A,
    const unsigned short* __restrict__ Bh_g, const unsigned short* __restrict__ Bl_g,
    const float* __restrict__ att_s, const float* __restrict__ att_d,
    unsigned short* __restrict__ h1b, float* __restrict__ asrc,
    float* __restrict__ adst, int M) {
  constexpr int K = 512, Nn = 256;
  constexpr int LDA = 40;
  __shared__ short Ah[128][LDA], Al[128][LDA];
  __shared__ short Bh[4 * 128 * 8], Bl[4 * 128 * 8];  // [quad][n_local][8]
  __shared__ float attLds[128][4];

  const int tid = threadIdx.x;
  const int wave = tid >> 6, lane = tid & 63;
  const int quad = lane >> 4, l16 = lane & 15;
  const int wm = (wave >> 1) * 64, wn = (wave & 1) * 64;
  const int rowBase = blockIdx.x * 128;
  const int colBase = blockIdx.y * 128;

  const int ra = tid >> 1, apart = (tid & 1) * 16;
  const int arow = min(rowBase + ra, M - 1);
  const float* aptr = A + (size_t)arow * K + apart;

  f32x4 acc[4][4] = {};

  for (int kc = 0; kc < K / 32; ++kc) {
    // ---- B tile: async global->LDS (4 chunks/thread: 2 hi + 2 lo) ----
#pragma unroll
    for (int inst = 0; inst < 2; ++inst) {
      int seq = inst * 256 + tid;
      int gq = seq >> 7, nl = seq & 127;
      size_t gsrc = (((size_t)kc * 4 + gq) * Nn + colBase + nl) * 8;
      GLDS16(Bh_g + gsrc, &Bh[seq * 8]);
      GLDS16(Bl_g + gsrc, &Bl[seq * 8]);
    }
    // ---- A tile: fp32 load, split, LDS store ----
    {
      alignas(16) short h[16], l[16];
      const float4* a4 = (const float4*)(aptr + kc * 32);
#pragma unroll
      for (int i = 0; i < 4; ++i) {
        float4 v = a4[i];
        split2(v.x, h[i * 4 + 0], l[i * 4 + 0]);
        split2(v.y, h[i * 4 + 1], l[i * 4 + 1]);
        split2(v.z, h[i * 4 + 2], l[i * 4 + 2]);
        split2(v.w, h[i * 4 + 3], l[i * 4 + 3]);
      }
      *(bf16x8*)&Ah[ra][apart]     = ((bf16x8*)h)[0];
      *(bf16x8*)&Ah[ra][apart + 8] = ((bf16x8*)h)[1];
      *(bf16x8*)&Al[ra][apart]     = ((bf16x8*)l)[0];
      *(bf16x8*)&Al[ra][apart + 8] = ((bf16x8*)l)[1];
    }
    __syncthreads();
    // ---- fragments + MFMA ----
    bf16x8 afh[4], afl[4], bfh[4], bfl[4];
#pragma unroll
    for (int mt = 0; mt < 4; ++mt) {
      afh[mt] = *(const bf16x8*)&Ah[wm + mt * 16 + l16][quad * 8];
      afl[mt] = *(const bf16x8*)&Al[wm + mt * 16 + l16][quad * 8];
    }
#pragma unroll
    for (int nt = 0; nt < 4; ++nt) {
      int bi = ((quad << 7) + wn + nt * 16 + l16) * 8;
      bfh[nt] = *(const bf16x8*)&Bh[bi];
      bfl[nt] = *(const bf16x8*)&Bl[bi];
    }
#pragma unroll
    for (int mt = 0; mt < 4; ++mt)
#pragma unroll
      for (int nt = 0; nt < 4; ++nt) {
        acc[mt][nt] = __builtin_amdgcn_mfma_f32_16x16x32_bf16(afh[mt], bfh[nt], acc[mt][nt], 0, 0, 0);
        acc[mt][nt] = __builtin_amdgcn_mfma_f32_16x16x32_bf16(afh[mt], bfl[nt], acc[mt][nt], 0, 0, 0);
        acc[mt][nt] = __builtin_amdgcn_mfma_f32_16x16x32_bf16(afl[mt], bfh[nt], acc[mt][nt], 0, 0, 0);
      }
    __syncthreads();
  }

  // ---- epilogue: bf16 store + fused attention dots ----
  float asw[4], adw[4];
#pragma unroll
  for (int nt = 0; nt < 4; ++nt) {
    int c = colBase + wn + nt * 16 + l16;
    asw[nt] = att_s[c];
    adw[nt] = att_d[c];
  }
#pragma unroll
  for (int mt = 0; mt < 4; ++mt) {
    int rl = wm + mt * 16 + quad * 4;
#pragma unroll
    for (int reg = 0; reg < 4; ++reg) {
      int r = rowBase + rl + reg;
      float s = 0.f, dd = 0.f;
#pragma unroll
      for (int nt = 0; nt < 4; ++nt) {
        float v = acc[mt][nt][reg];
        s += v * asw[nt];
        dd += v * adw[nt];
        if (r < M) {
          int c = colBase + wn + nt * 16 + l16;
          h1b[(size_t)r * Nn + c] = f2bf_rne(v);
        }
      }
#pragma unroll
      for (int off = 1; off < 16; off <<= 1) {
        s += __shfl_xor(s, off);
        dd += __shfl_xor(dd, off);
      }
      if (l16 == 0) {
        attLds[rl + reg][(wn >> 6) * 2 + 0] = s;
        attLds[rl + reg][(wn >> 6) * 2 + 1] = dd;
      }
    }
  }
  __syncthreads();
  if (tid < 128) {
    int r = rowBase + tid;
    if (r < M) {
      int hb = colBase >> 6;  // 0 or 2
      asrc[r * 4 + hb + 0] = attLds[tid][0];
      adst[r * 4 + hb + 0] = attLds[tid][1];
      asrc[r * 4 + hb + 1] = attLds[tid][2];
      adst[r * 4 + hb + 1] = attLds[tid][3];
    }
  }
}

// ============================================================
// GEMM2 fused: h2b = bf16(h1e @ W2), asrc2/adst2 = att dots.
// BM=128, BN=64 (full width = 1 head). WGM=4: wave -> 32 rows.
// ============================================================
__global__ __launch_bounds__(256) void gemm2_fused(
    const float* __restrict__ A,
    const unsigned short* __restrict__ Bh_g, const unsigned short* __restrict__ Bl_g,
    const float* __restrict__ att_s, const float* __restrict__ att_d,
    unsigned short* __restrict__ h2b, float* __restrict__ asrc,
    float* __restrict__ adst, int M) {
  constexpr int K = 256, Nn = 64;
  constexpr int LDA = 40;
  __shared__ short Ah[128][LDA], Al[128][LDA];
  __shared__ short Bh[4 * 64 * 8], Bl[4 * 64 * 8];  // [quad][n][8]
  __shared__ float attLds[128][2];

  const int tid = threadIdx.x;
  const int wave = tid >> 6, lane = tid & 63;
  const int quad = lane >> 4, l16 = lane & 15;
  const int wm = wave * 32;
  const int rowBase = blockIdx.x * 128;

  const int ra = tid >> 1, apart = (tid & 1) * 16;
  const int arow = min(rowBase + ra, M - 1);
  const float* aptr = A + (size_t)arow * K + apart;

  f32x4 acc[2][4] = {};

  for (int kc = 0; kc < K / 32; ++kc) {
    {
      size_t gsrc = (((size_t)kc * 4) * Nn) * 8 + (size_t)tid * 8;
      GLDS16(Bh_g + gsrc, &Bh[tid * 8]);
      GLDS16(Bl_g + gsrc, &Bl[tid * 8]);
    }
    {
      alignas(16) short h[16], l[16];
      const float4* a4 = (const float4*)(aptr + kc * 32);
#pragma unroll
      for (int i = 0; i < 4; ++i) {
        float4 v = a4[i];
        split2(v.x, h[i * 4 + 0], l[i * 4 + 0]);
        split2(v.y, h[i * 4 + 1], l[i * 4 + 1]);
        split2(v.z, h[i * 4 + 2], l[i * 4 + 2]);
        split2(v.w, h[i * 4 + 3], l[i * 4 + 3]);
      }
      *(bf16x8*)&Ah[ra][apart]     = ((bf16x8*)h)[0];
      *(bf16x8*)&Ah[ra][apart + 8] = ((bf16x8*)h)[1];
      *(bf16x8*)&Al[ra][apart]     = ((bf16x8*)l)[0];
      *(bf16x8*)&Al[ra][apart + 8] = ((bf16x8*)l)[1];
    }
    __syncthreads();
    bf16x8 afh[2], afl[2], bfh[4], bfl[4];
#pragma unroll
    for (int mt = 0; mt < 2; ++mt) {
      afh[mt] = *(const bf16x8*)&Ah[wm + mt * 16 + l16][quad * 8];
      afl[mt] = *(const bf16x8*)&Al[wm + mt * 16 + l16][quad * 8];
    }
#pragma unroll
    for (int nt = 0; nt < 4; ++nt) {
      int bi = ((quad << 6) + nt * 16 + l16) * 8;
      bfh[nt] = *(const bf16x8*)&Bh[bi];
      bfl[nt] = *(const bf16x8*)&Bl[bi];
    }
#pragma unroll
    for (int mt = 0; mt < 2; ++mt)
#pragma unroll
      for (int nt = 0; nt < 4; ++nt) {
        acc[mt][nt] = __builtin_amdgcn_mfma_f32_16x16x32_bf16(afh[mt], bfh[nt], acc[mt][nt], 0, 0, 0);
        acc[mt][nt] = __builtin_amdgcn_mfma_f32_16x16x32_bf16(afh[mt], bfl[nt], acc[mt][nt], 0, 0, 0);
        acc[mt][nt] = __builtin_amdgcn_mfma_f32_16x16x32_bf16(afl[mt], bfh[nt], acc[mt][nt], 0, 0, 0);
      }
    __syncthreads();
  }

  float asw[4], adw[4];
#pragma unroll
  for (int nt = 0; nt < 4; ++nt) {
    int c = nt * 16 + l16;
    asw[nt] = att_s[c];
    adw[nt] = att_d[c];
  }
#pragma unroll
  for (int mt = 0; mt < 2; ++mt) {
    int rl = wm + mt * 16 + quad * 4;
#pragma unroll
    for (int reg = 0; reg < 4; ++reg) {
      int r = rowBase + rl + reg;
      float s = 0.f, dd = 0.f;
#pragma unroll
      for (int nt = 0; nt < 4; ++nt) {
        float v = acc[mt][nt][reg];
        s += v * asw[nt];
        dd += v * adw[nt];
        if (r < M) {
          int c = nt * 16 + l16;
          h2b[(size_t)r * Nn + c] = f2bf_rne(v);
        }
      }
#pragma unroll
      for (int off = 1; off < 16; off <<= 1) {
        s += __shfl_xor(s, off);
        dd += __shfl_xor(dd, off);
      }
      if (l16 == 0) {
        attLds[rl + reg][0] = s;
        attLds[rl + reg][1] = dd;
      }
    }
  }
  __syncthreads();
  if (tid < 128) {
    int r = rowBase + tid;
    if (r < M) {
      asrc[r] = attLds[tid][0];
      adst[r] = attLds[tid][1];
    }
  }
}

// ============================================================
// Fused softmax + aggregation, layer 1 (H=4, C=64).
// ============================================================
__global__ __launch_bounds__(128) void agg_l1(
    const int* __restrict__ offs, const int* __restrict__ ssort,
    const float* __restrict__ asrc, const float* __restrict__ adst,
    const unsigned short* __restrict__ h1b, const float* __restrict__ b1,
    float* __restrict__ outp) {
  const int d = blockIdx.x;
  const int t = threadIdx.x;       // features 2t, 2t+1
  const int h = t >> 5;
  __shared__ int s_src[128];
  __shared__ float s_ex[128 * 4];
  const int row0 = offs[d], row1 = offs[d + 1];
  const float4 ad4 = *(const float4*)&adst[d * 4];
  float acc0 = 0.f, acc1 = 0.f, denom = 0.f;

  for (int j0 = row0; j0 < row1; j0 += 128) {
    const int n = min(128, row1 - j0);
    if (t < n) {
      int s = ssort[j0 + t];
      s_src[t] = s;
      float4 as = *(const float4*)&asrc[s * 4];
      float4 sc;
      sc.x = as.x + ad4.x; sc.x = sc.x > 0.f ? sc.x : 0.2f * sc.x;
      sc.y = as.y + ad4.y; sc.y = sc.y > 0.f ? sc.y : 0.2f * sc.y;
      sc.z = as.z + ad4.z; sc.z = sc.z > 0.f ? sc.z : 0.2f * sc.z;
      sc.w = as.w + ad4.w; sc.w = sc.w > 0.f ? sc.w : 0.2f * sc.w;
      sc.x = __expf(sc.x); sc.y = __expf(sc.y);
      sc.z = __expf(sc.z); sc.w = __expf(sc.w);
      *(float4*)&s_ex[t * 4] = sc;
    }
    __syncthreads();
    for (int j = 0; j < n; ++j) {
      float exv = s_ex[j * 4 + h];
      unsigned pv = *(const unsigned*)&h1b[(size_t)s_src[j] * 256 + 2 * t];
      float f0 = __uint_as_float(pv << 16);
      float f1 = __uint_as_float(pv & 0xFFFF0000u);
      acc0 += f0 * exv;
      acc1 += f1 * exv;
      denom += exv;
    }
    __syncthreads();
  }
  float inv = denom > 0.f ? 1.f / denom : 0.f;
  float v0 = acc0 * inv + b1[2 * t];
  float v1 = acc1 * inv + b1[2 * t + 1];
  float2 r;
  r.x = v0 > 0.f ? v0 : expm1f(v0);
  r.y = v1 > 0.f ? v1 : expm1f(v1);
  *(float2*)&outp[(size_t)d * 256 + 2 * t] = r;
}

// ============================================================
// Fused softmax + aggregation, layer 2 (H=1, C=64), bf16 gather.
// ============================================================
__global__ __launch_bounds__(256) void agg_l2(
    const int* __restrict__ offs, const int* __restrict__ ssort,
    const float* __restrict__ asrc, const float* __restrict__ adst,
    const unsigned short* __restrict__ h2b, const float* __restrict__ b2,
    float* __restrict__ outp, int n_nodes) {
  int d = blockIdx.x * 4 + (threadIdx.x >> 6);
  int lane = threadIdx.x & 63;
  if (d >= n_nodes) return;
  const int row0 = offs[d], row1 = offs[d + 1];
  const float ad = adst[d];
  float acc = 0.f, denom = 0.f;

  for (int j0 = row0; j0 < row1; j0 += 64) {
    const int n = min(64, row1 - j0);
    int s = 0;
    float ex = 0.f;
    if (lane < n) {
      s = ssort[j0 + lane];
      float sc = asrc[s] + ad;
      sc = sc > 0.f ? sc : 0.2f * sc;
      ex = __expf(sc);
    }
    float ds = ex;
#pragma unroll
    for (int off = 32; off > 0; off >>= 1) ds += __shfl_xor(ds, off);
    denom += ds;
    for (int j = 0; j < n; ++j) {
      int sj = __shfl(s, j);
      float exj = __shfl(ex, j);
      float f = __uint_as_float((unsigned)h2b[(size_t)sj * 64 + lane] << 16);
      acc += f * exj;
    }
  }
  float val = (denom > 0.f ? acc / denom : 0.f) + b2[lane];
  outp[(size_t)d * 64 + lane] = val;
}

// ============================================================
// final MLP head
// ============================================================
__global__ __launch_bounds__(256) void mlp_head(
    const float* __restrict__ emb_in,
    const float* __restrict__ mw1, const float* __restrict__ mb1,
    const float* __restrict__ mw2, const float* __restrict__ mb2,
    float* __restrict__ outp, int n) {
  __shared__ float w1s[64 * 64];
  __shared__ float w2s[64 * 40];
  __shared__ float b1s[64];
  __shared__ float b2s[40];
  int t = threadIdx.x;
  for (int i = t; i < 64 * 64; i += 256) w1s[i] = mw1[i];
  for (int i = t; i < 64 * 40; i += 256) w2s[i] = mw2[i];
  if (t < 64) b1s[t] = mb1[t];
  if (t < 40) b2s[t] = mb2[t];
  __syncthreads();
  int node = blockIdx.x * 256 + t;
  if (node >= n) return;
  float emb[64];
#pragma unroll
  for (int i = 0; i < 64; ++i) emb[i] = emb_in[(size_t)node * 64 + i];
  float hid[64];
#pragma unroll
  for (int j = 0; j < 64; ++j) {
    float s = b1s[j];
#pragma unroll
    for (int i = 0; i < 64; ++i) s += emb[i] * w1s[i * 64 + j];
    hid[j] = s > 0.f ? s : 0.f;
  }
#pragma unroll
  for (int k = 0; k < 40; ++k) {
    float s = b2s[k];
#pragma unroll
    for (int j = 0; j < 64; ++j) s += hid[j] * w2s[j * 40 + k];
    outp[(size_t)node * 40 + k] = s;
  }
}

extern "C" void kernel_launch(void* const* d_in, const int* in_sizes, int n_in,
                              void* d_out, int out_size, void* d_ws, size_t ws_size,
                              hipStream_t stream) {
  const float* x        = (const float*)d_in[0];
  const int*   ei       = (const int*)d_in[1];
  const float* W1       = (const float*)d_in[2];
  const float* att_src1 = (const float*)d_in[3];
  const float* att_dst1 = (const float*)d_in[4];
  const float* b1       = (const float*)d_in[5];
  const float* W2       = (const float*)d_in[6];
  const float* att_src2 = (const float*)d_in[7];
  const float* att_dst2 = (const float*)d_in[8];
  const float* b2       = (const float*)d_in[9];
  const float* mw1      = (const float*)d_in[10];
  const float* mb1      = (const float*)d_in[11];
  const float* mw2      = (const float*)d_in[12];
  const float* mb2      = (const float*)d_in[13];
  float* out = (float*)d_out;

  const int N = N_NODES, E = N_EDGES;
  char* base = (char*)d_ws;
  size_t o = 0;
  auto alloc = [&](size_t n_elems) {   // float-unit (4 B) allocator
    void* p = base + o;
    o += n_elems * 4;
    return p;
  };
  int* cnt = (int*)alloc(N);
  int* cur = (int*)alloc(N);
  size_t zero_bytes = o;
  int*   offs  = (int*)alloc(N + 2);
  int*   bsum  = (int*)alloc(256);
  int*   bofs  = (int*)alloc(256);
  int*   ssort = (int*)alloc(E);
  float* h1e   = (float*)alloc((size_t)N * 256);
  float* asrc1 = (float*)alloc((size_t)N * 4);
  float* adst1 = (float*)alloc((size_t)N * 4);
  float* emb   = (float*)alloc((size_t)N * 64);
  float* asrc2 = (float*)alloc(N);
  float* adst2 = (float*)alloc(N);
  unsigned short* h1b = (unsigned short*)alloc((size_t)N * 128);  // N*256 bf16
  unsigned short* h2b = (unsigned short*)alloc((size_t)N * 32);   // N*64 bf16
  unsigned short* w1h = (unsigned short*)alloc(512 * 256 / 2);
  unsigned short* w1l = (unsigned short*)alloc(512 * 256 / 2);
  unsigned short* w2h = (unsigned short*)alloc(256 * 64 / 2);
  unsigned short* w2l = (unsigned short*)alloc(256 * 64 / 2);

  hipMemsetAsync(d_ws, 0, zero_bytes, stream);

  const int EB = (E + 255) / 256;

  // ---- build dst-sorted CSR + weight pre-split ----
  hist_k<<<EB, 256, 0, stream>>>(ei, cnt);
  scan1<<<SCAN_B, 256, 0, stream>>>(cnt, offs, bsum);
  scan2<<<1, 256, 0, stream>>>(bsum, bofs);
  scan3<<<SCAN_B, 256, 0, stream>>>(offs, bofs);
  scatter_k<<<EB, 256, 0, stream>>>(ei, offs, cur, ssort);
  wsplit<<<(512 / 8 * 256 + 255) / 256, 256, 0, stream>>>(W1, w1h, w1l, 512, 256);
  wsplit<<<(256 / 8 * 64 + 255) / 256, 256, 0, stream>>>(W2, w2h, w2l, 256, 64);

  // ---- layer 1 ----
  dim3 g1((N + 127) / 128, 2);
  gemm1_fused<<<g1, 256, 0, stream>>>(x, w1h, w1l, att_src1, att_dst1,
                                      h1b, asrc1, adst1, N);
  agg_l1<<<N, 128, 0, stream>>>(offs, ssort, asrc1, adst1, h1b, b1, h1e);

  // ---- layer 2 ----
  dim3 g2((N + 127) / 128, 1);
  gemm2_fused<<<g2, 256, 0, stream>>>(h1e, w2h, w2l, att_src2, att_dst2,
                                      h2b, asrc2, adst2, N);
  agg_l2<<<(N + 3) / 4, 256, 0, stream>>>(offs, ssort, asrc2, adst2, h2b, b2, emb, N);

  // ---- MLP head ----
  mlp_head<<<(N + 255) / 256, 256, 0, stream>>>(emb, mw1, mb1, mw2, mb2, out, N);
}